// Round 10
// baseline (209.251 us; speedup 1.0000x reference)
//
#include <hip/hip_runtime.h>
#include <hip/hip_cooperative_groups.h>
#include <math.h>
#include <stdint.h>

namespace cg = cooperative_groups;

#define B_SZ 2048
#define N_SZ 16384
#define D_SZ 64
#define P_SZ 5
#define BM 128
#define BN 128
#define NPAIR 1024            // 16 user-blocks x 64 item-pairs
#define INVLN2 1.44269504088896340736f
#define LN2    0.69314718055994530942f

typedef __bf16 bf16x8 __attribute__((ext_vector_type(8)));
typedef float f32x4 __attribute__((ext_vector_type(4)));

// ws float-unit layout
#define WS_U2   0                      // [2048]
#define WS_V2   (WS_U2 + B_SZ)         // [16384]
#define WS_CE   (WS_V2 + N_SZ)         // [2048] per-block ce partials
#define WS_PART (WS_CE + B_SZ)         // [64][2048] per-(item-pair,user) S partials
#define WS_UBF  (WS_PART + 64 * B_SZ)  // bf16[2048][64] swizzled rows
#define WS_VBF  (WS_UBF + B_SZ * D_SZ / 2)

__device__ __forceinline__ float fexp2(float x) { return __builtin_amdgcn_exp2f(x); }

#define GLD_LDS(g, s) __builtin_amdgcn_global_load_lds( \
    (const __attribute__((address_space(1))) void*)(g), \
    (__attribute__((address_space(3))) void*)(s), 16, 0, 0)

// swizzled byte offset of 16B-group g16 in row `row` of a [128][64]bf16 tile
#define SWZ(row, g16) (((row) << 7) + ((((g16) ^ ((row) & 7))) << 4))

// manual LDS layout (bytes) — keeps total < 40 KB for 4 blocks/CU
#define SM_UT 0        // bf16[128][64]   16384
#define SM_VT 16384    // bf16[128][64]   16384
#define SM_U2 32768    // float[128]      (aliased: phase5/6 reduce scratch)
#define SM_MS 33280    // float[128]
#define SM_CV 33792    // float[2][128]
#define SM_CI 34816    // int[2][128]
#define SM_ID 35840    // int[128][6]
#define SM_BL 38912    // uint[256] bloom (8192 bits); aliased float part[256]
#define SM_FW 39936    // ull[2][2]
#define SM_SZ 39968

__global__ __launch_bounds__(256, 4) void mega_k(const float* __restrict__ uem,
                                                 const float* __restrict__ vem,
                                                 const float* __restrict__ target,
                                                 const int* __restrict__ iidx,
                                                 const int* __restrict__ pidx,
                                                 float* __restrict__ ws,
                                                 float* __restrict__ out) {
    __shared__ __attribute__((aligned(16))) char smem[SM_SZ];
    const char* UtB = smem + SM_UT;
    const char* VtB = smem + SM_VT;
    float* u2F = (float*)(smem + SM_U2);
    float* msF = (float*)(smem + SM_MS);
    float* colv2A = (float*)(smem + SM_CV);
    int* colidA = (int*)(smem + SM_CI);
    int* idsA = (int*)(smem + SM_ID);
    unsigned* bloomU = (unsigned*)(smem + SM_BL);
    unsigned long long* flagwA = (unsigned long long*)(smem + SM_FW);

    const int t = threadIdx.x;
    const int bid = blockIdx.x;
    const int G = gridDim.x;
    const int w = t >> 6, l = t & 63;
    cg::grid_group grid = cg::this_grid();

    // ---- phase 1: fp32 -> swizzled bf16 rows + norms (grid-stride) ----
    for (int g0 = bid * 256 + t; g0 < (B_SZ + N_SZ) * 8; g0 += G * 256) {
        int row = g0 >> 3, grp = g0 & 7;
        bool isU = row < B_SZ;
        int r = isU ? row : row - B_SZ;
        const float* src = (isU ? uem : vem) + (size_t)r * D_SZ + grp * 8;
        float4 a = ((const float4*)src)[0];
        float4 b = ((const float4*)src)[1];
        float nrm = a.x * a.x + a.y * a.y + a.z * a.z + a.w * a.w +
                    b.x * b.x + b.y * b.y + b.z * b.z + b.w * b.w;
#pragma unroll
        for (int o = 1; o < 8; o <<= 1) nrm += __shfl_xor(nrm, o);
        uint16_t* dst = (uint16_t*)(ws + (isU ? WS_UBF : WS_VBF)) +
                        (size_t)r * D_SZ + ((grp ^ (r & 7)) * 8);
        bf16x8 h = {(__bf16)a.x, (__bf16)a.y, (__bf16)a.z, (__bf16)a.w,
                    (__bf16)b.x, (__bf16)b.y, (__bf16)b.z, (__bf16)b.w};
        *(bf16x8*)dst = h;
        if (grp == 0) ws[(isU ? WS_U2 : WS_V2) + r] = nrm;
    }
    grid.sync();

    // ---- phase 3: GEMM over item-pairs (grid-stride) ----
    const int wi = w >> 1, wu = w & 1, lr = l & 15, kg = l >> 4;
    for (int p = bid; p < NPAIR; p += G) {
        int x = p & 7, rest = p >> 3;
        int i = x * 8 + (rest & 7);          // item-pair 0..63 (XCD slab)
        int by = rest >> 3;                  // user block 0..15
        int brow = by * BM;
        int bx0 = i * 2;

        bloomU[t] = 0u;
        {   // stage U + V(tile0), pre-swizzled linear copies
            const char* gu = (const char*)ws + (size_t)WS_UBF * 4 + brow * 128 + w * 4096 + l * 16;
            const char* gv = (const char*)ws + (size_t)WS_VBF * 4 + (size_t)bx0 * BN * 128 + w * 4096 + l * 16;
            char* lu = (char*)smem + SM_UT + w * 4096;
            char* lv = (char*)smem + SM_VT + w * 4096;
#pragma unroll
            for (int q = 0; q < 4; ++q) {
                GLD_LDS(gu + q * 1024, lu + q * 1024);
                GLD_LDS(gv + q * 1024, lv + q * 1024);
            }
        }
        if (t < BM) {
            int U = brow + t;
            float tg = target[U];
            float sg = (tg > 0.f) ? 1.f : ((tg < 0.f) ? -1.f : 0.f);
            msF[t] = -0.5f * INVLN2 * sg;
            u2F[t] = ws[WS_U2 + U];
            const int* pp = pidx + (size_t)U * P_SZ;
            int* d = idsA + t * 6;
            d[0] = pp[0]; d[1] = pp[1]; d[2] = pp[2]; d[3] = pp[3]; d[4] = pp[4];
            d[5] = iidx[U];
            colidA[t] = iidx[bx0 * BN + t];
            colv2A[t] = ws[WS_V2 + bx0 * BN + t];
            colidA[128 + t] = iidx[bx0 * BN + BN + t];
            colv2A[128 + t] = ws[WS_V2 + bx0 * BN + BN + t];
        }
        __syncthreads();                      // bar1: tiles + scalars staged
        if (t < BM) {
            const int* d = idsA + t * 6;
#pragma unroll
            for (int j = 0; j < 6; ++j) {
                unsigned h = (unsigned)d[j] & 8191u;
                atomicOr(&bloomU[h >> 5], 1u << (h & 31));
            }
        }
        __syncthreads();                      // bar2: bloom built
        {   // wave w covers tile (w>>1), half (w&1)
            unsigned h = (unsigned)colidA[(w >> 1) * 128 + (w & 1) * 64 + l] & 8191u;
            bool f = (bloomU[h >> 5] >> (h & 31)) & 1u;
            unsigned long long bal = __ballot(f);
            if (l == 0) flagwA[w] = bal;      // flagw[tile][half]
        }

        float Sacc[4] = {0.f, 0.f, 0.f, 0.f};
        f32x4 acc[4][4];

#define MFMA_TILE() do {                                                          \
    _Pragma("unroll") for (int it2 = 0; it2 < 4; ++it2)                           \
    _Pragma("unroll") for (int ut2 = 0; ut2 < 4; ++ut2)                           \
        acc[it2][ut2] = (f32x4){0.f, 0.f, 0.f, 0.f};                              \
    _Pragma("unroll") for (int kk = 0; kk < 2; ++kk) {                            \
        bf16x8 afk[4];                                                            \
        _Pragma("unroll") for (int it2 = 0; it2 < 4; ++it2)                       \
            afk[it2] = *(const bf16x8*)(VtB + SWZ(wi * 64 + it2 * 16 + lr, kk * 4 + kg)); \
        _Pragma("unroll") for (int ut2 = 0; ut2 < 4; ++ut2) {                     \
            bf16x8 bu = *(const bf16x8*)(UtB + SWZ(wu * 64 + ut2 * 16 + lr, kk * 4 + kg)); \
            _Pragma("unroll") for (int it2 = 0; it2 < 4; ++it2)                   \
                acc[it2][ut2] = __builtin_amdgcn_mfma_f32_16x16x32_bf16(afk[it2], bu, acc[it2][ut2], 0, 0, 0); \
        }                                                                         \
    }                                                                             \
} while (0)

#define EPILOG(TT) do {                                                           \
    const unsigned long long fm = flagwA[(TT) * 2 + wi];                          \
    f32x4 v2q[4]; unsigned nib[4];                                                \
    _Pragma("unroll") for (int it2 = 0; it2 < 4; ++it2) {                         \
        v2q[it2] = *(const f32x4*)&colv2A[(TT) * 128 + wi * 64 + it2 * 16 + kg * 4]; \
        nib[it2] = ((unsigned)(fm >> (it2 * 16 + kg * 4))) & 0xFu;                \
    }                                                                             \
    _Pragma("unroll") for (int ut2 = 0; ut2 < 4; ++ut2) {                         \
        const int ur = wu * 64 + ut2 * 16 + lr;                                   \
        const float u2r = u2F[ur];                                                \
        const float msg2 = msF[ur];                                               \
        const float c1 = -2.f * msg2;                                             \
        float Sl = 0.f;                                                           \
        _Pragma("unroll") for (int it2 = 0; it2 < 4; ++it2) {                     \
            f32x4 bt;                                                             \
            _Pragma("unroll") for (int r2 = 0; r2 < 4; ++r2)                      \
                bt[r2] = (u2r + v2q[it2][r2]) * msg2;                             \
            _Pragma("unroll") for (int r2 = 0; r2 < 4; ++r2) {                    \
                float v = fminf(fmaf(c1, acc[it2][ut2][r2], bt[r2]), 0.f);        \
                Sl += fexp2(v);                                                   \
            }                                                                     \
            if (nib[it2]) {                                                       \
                const int* q = idsA + ur * 6;                                     \
                _Pragma("unroll") for (int r2 = 0; r2 < 4; ++r2) {                \
                    if ((nib[it2] >> r2) & 1u) {                                  \
                        int c = colidA[(TT) * 128 + wi * 64 + it2 * 16 + kg * 4 + r2]; \
                        if ((c == q[0]) | (c == q[1]) | (c == q[2]) |             \
                            (c == q[3]) | (c == q[4]) | (c == q[5])) {            \
                            float v = fminf(fmaf(c1, acc[it2][ut2][r2], bt[r2]), 0.f); \
                            Sl -= fexp2(v);                                       \
                        }                                                         \
                    }                                                             \
                }                                                                 \
            }                                                                     \
        }                                                                         \
        Sacc[ut2] += Sl;                                                          \
    }                                                                             \
} while (0)

        // tile 0
        MFMA_TILE();
        __syncthreads();                      // bar3: all waves done reading Vt
        {   // issue V(tile1) stage; epilogue0 overlaps the load latency
            const char* gv = (const char*)ws + (size_t)WS_VBF * 4 + (size_t)(bx0 + 1) * BN * 128 + w * 4096 + l * 16;
            char* lv = (char*)smem + SM_VT + w * 4096;
#pragma unroll
            for (int q = 0; q < 4; ++q) GLD_LDS(gv + q * 1024, lv + q * 1024);
        }
        EPILOG(0);
        __syncthreads();                      // bar4: V1 staged
        // tile 1
        MFMA_TILE();
        EPILOG(1);

        // block-level merge -> one store per (pair, user)
        float* part = (float*)(smem + SM_BL); // bloom dead
#pragma unroll
        for (int ut2 = 0; ut2 < 4; ++ut2) {
            float Sl = Sacc[ut2];
            Sl += __shfl_xor(Sl, 16);
            Sl += __shfl_xor(Sl, 32);
            if (kg == 0) part[wi * 128 + wu * 64 + ut2 * 16 + lr] = Sl;
        }
        __syncthreads();                      // bar5
        if (t < BM)
            ws[WS_PART + (size_t)i * B_SZ + brow + t] = part[t] + part[128 + t];
        __syncthreads();                      // bar6: safe for next iteration
    }
    grid.sync();

    // ---- phase 5: per-row merge + exact fp32 diagonal + ce ----
    float* ceL = (float*)(smem + SM_U2);      // scratch
    float ce_acc = 0.f;
    for (int r0 = bid * 2; r0 < B_SZ; r0 += G * 2) {
        if (w < 2) {
            int r = r0 + w;
            float S = ws[WS_PART + (size_t)l * B_SZ + r];
#pragma unroll
            for (int o = 1; o < 64; o <<= 1) S += __shfl_xor(S, o);
            float d2l = 0.f;
            if (l < 16) {
                float4 a = ((const float4*)(uem + (size_t)r * D_SZ))[l];
                float4 b = ((const float4*)(vem + (size_t)r * D_SZ))[l];
                float dx = a.x - b.x, dy = a.y - b.y, dz = a.z - b.z, dw2 = a.w - b.w;
                d2l = dx * dx + dy * dy + dz * dz + dw2 * dw2;
            }
#pragma unroll
            for (int o = 1; o < 16; o <<= 1) d2l += __shfl_xor(d2l, o);
            if (l == 0) {
                float tg = target[r];
                float sg = (tg > 0.f) ? 1.f : ((tg < 0.f) ? -1.f : 0.f);
                float p2 = -0.5f * INVLN2 * sg * d2l;   // diagonal logit (log2 dom)
                float ce = LN2 * (__log2f(fexp2(p2) + S) - p2);
                ceL[w] = ce * fabsf(tg);
            }
        }
        __syncthreads();
        if (t == 0) ce_acc += ceL[0] + ceL[1];
        __syncthreads();
    }
    if (t == 0) ws[WS_CE + bid] = ce_acc;
    grid.sync();

    // ---- phase 6: block 0 final reduce ----
    if (bid == 0) {
        float c = 0.f;
        for (int j = t; j < G; j += 256) c += ws[WS_CE + j];
#pragma unroll
        for (int o = 32; o > 0; o >>= 1) c += __shfl_down(c, o);
        float* sred = (float*)(smem + SM_U2);
        if (l == 0) sred[w] = c;
        __syncthreads();
        if (t == 0) out[0] = sred[0] + sred[1] + sred[2] + sred[3];
    }
}

extern "C" void kernel_launch(void* const* d_in, const int* in_sizes, int n_in,
                              void* d_out, int out_size, void* d_ws, size_t ws_size,
                              hipStream_t stream) {
    const float* uem = (const float*)d_in[0];
    const float* vem = (const float*)d_in[1];
    const float* target = (const float*)d_in[2];
    const int* iidx = (const int*)d_in[3];
    const int* pidx = (const int*)d_in[4];
    float* ws = (float*)d_ws;
    float* out = (float*)d_out;

    int nb = 0;
    hipOccupancyMaxActiveBlocksPerMultiprocessor(&nb, (const void*)mega_k, 256, 0);
    if (nb < 1) nb = 1;
    int G = nb * 256;
    if (G > 1024) G = 1024;

    void* args[] = {(void*)&uem, (void*)&vem, (void*)&target,
                    (void*)&iidx, (void*)&pidx, (void*)&ws, (void*)&out};
    hipLaunchCooperativeKernel((const void*)mega_k, dim3(G), dim3(256), args, 0, stream);
}

// Round 11
// 109.171 us; speedup vs baseline: 1.9167x; 1.9167x over previous
//
#include <hip/hip_runtime.h>
#include <math.h>
#include <stdint.h>

#define B_SZ 2048
#define N_SZ 16384
#define D_SZ 64
#define P_SZ 5

#define BM 128
#define BN 128
#define NCB (N_SZ / BN)   // 128
#define INVLN2 1.44269504088896340736f
#define LN2    0.69314718055994530942f

typedef __bf16 bf16x8 __attribute__((ext_vector_type(8)));
typedef __bf16 bf16x4 __attribute__((ext_vector_type(4)));
typedef float f32x4 __attribute__((ext_vector_type(4)));

// ws layout (float units): only the per-(item-block, user) partial sums
#define WS_PART 0     // [NCB][B_SZ] = 128*2048 floats = 1 MB

__device__ __forceinline__ float fexp2(float x) { return __builtin_amdgcn_exp2f(x); }

// swizzled byte offset of 16B-group g16 in row `row` of a [128][64]bf16 tile
#define SWZ(row, g16) (((row) << 7) + ((((g16) ^ ((row) & 7))) << 4))

__global__ __launch_bounds__(256, 4) void dist_k(const float* __restrict__ uem,
                                                 const float* __restrict__ vem,
                                                 const float* __restrict__ target,
                                                 const int* __restrict__ iidx,
                                                 const int* __restrict__ pidx,
                                                 float* __restrict__ ws) {
    __shared__ __bf16 Ut[BM * D_SZ];         // 16 KB, swizzled rows
    __shared__ __bf16 Vt[BN * D_SZ];         // 16 KB, swizzled rows
    __shared__ float u2s[BM];
    __shared__ float msgs[BM];
    __shared__ float colv2[BN];
    __shared__ int ids[BM * 6];              // p0..p4 + own id per user
    __shared__ int colid[BN];
    __shared__ unsigned int bloom[512];      // 16384-bit filter; ALIASED as part[256] after bar3
    __shared__ unsigned long long flagw[2];  // per wi-half flagged-column bits

    const int t = threadIdx.x;
    const int orig = blockIdx.x;
    const int bx = (orig & 7) * 16 + ((orig >> 3) & 15);   // item block (XCD slab)
    const int by = orig >> 7;                              // user block
    const int brow = by * BM, bcol = bx * BN;

    bloom[t] = 0u;
    bloom[256 + t] = 0u;

    // ---- fused stage: fp32 global -> (norms via shfl) + bf16 swizzled LDS ----
    {
        const float4* su = (const float4*)(uem + (size_t)brow * D_SZ);
        const float4* sv = (const float4*)(vem + (size_t)bcol * D_SZ);
        for (int i = 0; i < 8; ++i) {
            int f = i * 256 + t;
            int row = f >> 4, seg = f & 15, g = seg >> 1, p = seg & 1;
            float4 x = su[f];
            float4 y = sv[f];
            float nu = x.x * x.x + x.y * x.y + x.z * x.z + x.w * x.w;
            float nv = y.x * y.x + y.y * y.y + y.z * y.z + y.w * y.w;
#pragma unroll
            for (int o = 1; o < 16; o <<= 1) {
                nu += __shfl_xor(nu, o);
                nv += __shfl_xor(nv, o);
            }
            if (seg == 0) {
                u2s[row] = nu;
                colv2[row] = nv;
            }
            *(bf16x4*)((char*)Ut + SWZ(row, g) + p * 8) =
                (bf16x4){(__bf16)x.x, (__bf16)x.y, (__bf16)x.z, (__bf16)x.w};
            *(bf16x4*)((char*)Vt + SWZ(row, g) + p * 8) =
                (bf16x4){(__bf16)y.x, (__bf16)y.y, (__bf16)y.z, (__bf16)y.w};
        }
    }
    if (t < BM) {
        int U = brow + t;
        float tg = target[U];
        float sg = (tg > 0.f) ? 1.f : ((tg < 0.f) ? -1.f : 0.f);
        msgs[t] = -0.5f * INVLN2 * sg;       // log2-domain sign factor (<= 0)
        const int* pp = pidx + (size_t)U * P_SZ;
        int* d = &ids[t * 6];
        d[0] = pp[0]; d[1] = pp[1]; d[2] = pp[2]; d[3] = pp[3]; d[4] = pp[4];
        d[5] = iidx[U];
        colid[t] = iidx[bcol + t];
    }
    __syncthreads();                         // bar1: tiles + scalars complete
    if (t < BM) {
        const int* d = &ids[t * 6];
#pragma unroll
        for (int j = 0; j < 6; ++j) {
            unsigned int h = (unsigned)d[j] & 16383u;
            atomicOr(&bloom[h >> 5], 1u << (h & 31));
        }
    }
    __syncthreads();                         // bar2: bloom built
    if ((t >> 6) < 2) {                      // waves 0,1: flag bits per wi-half
        int l = t & 63;
        unsigned int h = (unsigned)colid[(t >> 6) * 64 + l] & 16383u;
        bool f = (bloom[h >> 5] >> (h & 31)) & 1u;
        unsigned long long bal = __ballot(f);
        if (l == 0) flagw[t >> 6] = bal;
    }

    // ---- MFMA: A=items, B=users, frags from swizzled LDS ----
    const int w = t >> 6, l = t & 63;
    const int wi = w >> 1, wu = w & 1, lr = l & 15, kg = l >> 4;
    const char* UtB = (const char*)Ut;
    const char* VtB = (const char*)Vt;
    f32x4 acc[4][4];                         // [it][ut]
#pragma unroll
    for (int it = 0; it < 4; ++it)
#pragma unroll
        for (int ut = 0; ut < 4; ++ut)
            acc[it][ut] = (f32x4){0.f, 0.f, 0.f, 0.f};
#pragma unroll
    for (int kk = 0; kk < 2; ++kk) {
        bf16x8 afk[4];
#pragma unroll
        for (int it = 0; it < 4; ++it)
            afk[it] = *(const bf16x8*)(VtB + SWZ(wi * 64 + it * 16 + lr, kk * 4 + kg));
#pragma unroll
        for (int ut = 0; ut < 4; ++ut) {
            bf16x8 bu = *(const bf16x8*)(UtB + SWZ(wu * 64 + ut * 16 + lr, kk * 4 + kg));
#pragma unroll
            for (int it = 0; it < 4; ++it)
                acc[it][ut] = __builtin_amdgcn_mfma_f32_16x16x32_bf16(afk[it], bu, acc[it][ut], 0, 0, 0);
        }
    }
    __syncthreads();                         // bar3: flagw visible; bloom dead -> alias as part
    float* part = (float*)bloom;             // [2][BM] floats (1 KB of the 2 KB region)

    // ---- epilogue: branch-free exp2 sum; rare flagged columns subtracted ----
    f32x4 v2q[4];
    unsigned nib[4];
    const unsigned long long fm = flagw[wi];
#pragma unroll
    for (int it = 0; it < 4; ++it) {
        v2q[it] = *(const f32x4*)&colv2[wi * 64 + it * 16 + kg * 4];
        nib[it] = ((unsigned)(fm >> (it * 16 + kg * 4))) & 0xFu;
    }
#pragma unroll
    for (int ut = 0; ut < 4; ++ut) {
        const int ur = wu * 64 + ut * 16 + lr;   // user = C col (lane&15)
        const float u2r = u2s[ur];
        const float msg2 = msgs[ur];
        const float c1 = -2.f * msg2;            // >= 0
        float Sl = 0.f;
#pragma unroll
        for (int it = 0; it < 4; ++it) {
            f32x4 bt;
#pragma unroll
            for (int r = 0; r < 4; ++r) bt[r] = (u2r + v2q[it][r]) * msg2;
#pragma unroll
            for (int r = 0; r < 4; ++r) {
                float v = fminf(fmaf(c1, acc[it][ut][r], bt[r]), 0.f);
                Sl += fexp2(v);
            }
            if (nib[it]) {                       // rare: flagged column in this group
                const int* q = &ids[ur * 6];
#pragma unroll
                for (int r = 0; r < 4; ++r) {
                    if ((nib[it] >> r) & 1u) {
                        int c = colid[wi * 64 + it * 16 + kg * 4 + r];
                        if ((c == q[0]) | (c == q[1]) | (c == q[2]) |
                            (c == q[3]) | (c == q[4]) | (c == q[5])) {
                            float v = fminf(fmaf(c1, acc[it][ut][r], bt[r]), 0.f);
                            Sl -= fexp2(v);      // exact cancel of masked term
                        }
                    }
                }
            }
        }
        Sl += __shfl_xor(Sl, 16);
        Sl += __shfl_xor(Sl, 32);
        if (kg == 0) part[wi * BM + ur] = Sl;    // unique slot per (wi, user)
    }
    __syncthreads();                         // bar4: partials in LDS
    if (t < BM)
        ws[WS_PART + (size_t)bx * B_SZ + brow + t] = part[t] + part[BM + t];
}

// wave per row: merge 128 partials + exact fp32 diagonal + ce
__global__ __launch_bounds__(256) void finish_k(const float* __restrict__ uem,
                                                const float* __restrict__ vem,
                                                const float* __restrict__ target,
                                                const float* __restrict__ ws,
                                                float* __restrict__ out) {
    const int wv = threadIdx.x >> 6, l = threadIdx.x & 63;
    const int r = blockIdx.x * 4 + wv;

    float S = ws[WS_PART + (size_t)l * B_SZ + r] +
              ws[WS_PART + (size_t)(64 + l) * B_SZ + r];
#pragma unroll
    for (int o = 1; o < 64; o <<= 1) S += __shfl_xor(S, o);

    float d2l = 0.f;
    if (l < 16) {
        float4 a = ((const float4*)(uem + (size_t)r * D_SZ))[l];
        float4 b = ((const float4*)(vem + (size_t)r * D_SZ))[l];
        float dx = a.x - b.x, dy = a.y - b.y, dz = a.z - b.z, dw = a.w - b.w;
        d2l = dx * dx + dy * dy + dz * dz + dw * dw;
    }
#pragma unroll
    for (int o = 1; o < 16; o <<= 1) d2l += __shfl_xor(d2l, o);

    __shared__ float cred[4];
    if (l == 0) {
        float tg = target[r];
        float sg = (tg > 0.f) ? 1.f : ((tg < 0.f) ? -1.f : 0.f);
        float p2 = -0.5f * INVLN2 * sg * d2l;          // diagonal logit, log2 domain
        float ce = LN2 * (__log2f(fexp2(p2) + S) - p2);
        cred[wv] = ce * fabsf(tg);
    }
    __syncthreads();
    if (threadIdx.x == 0)
        atomicAdd(out, cred[0] + cred[1] + cred[2] + cred[3]);
}

extern "C" void kernel_launch(void* const* d_in, const int* in_sizes, int n_in,
                              void* d_out, int out_size, void* d_ws, size_t ws_size,
                              hipStream_t stream) {
    const float* uem = (const float*)d_in[0];
    const float* vem = (const float*)d_in[1];
    const float* target = (const float*)d_in[2];
    const int* iidx = (const int*)d_in[3];
    const int* pidx = (const int*)d_in[4];
    float* ws = (float*)d_ws;
    float* out = (float*)d_out;

    hipMemsetAsync(out, 0, sizeof(float), stream);

    // A/B-by-replication: dist_k writes are idempotent pure stores, so launching
    // it 3x is semantically identical. dist_dur = (T_R11 - T_R9) / 2.
    dist_k<<<dim3(NCB * (B_SZ / BM)), dim3(256), 0, stream>>>(uem, vem, target, iidx, pidx, ws);
    dist_k<<<dim3(NCB * (B_SZ / BM)), dim3(256), 0, stream>>>(uem, vem, target, iidx, pidx, ws);
    dist_k<<<dim3(NCB * (B_SZ / BM)), dim3(256), 0, stream>>>(uem, vem, target, iidx, pidx, ws);

    finish_k<<<dim3(B_SZ / 4), dim3(256), 0, stream>>>(uem, vem, target, ws, out);
}